// Round 4
// baseline (87.981 us; speedup 1.0000x reference)
//
#include <hip/hip_runtime.h>
#include <math.h>

// Ewald real-space pair sum, symmetric half-enumeration, single fused kernel:
//   out = (NORM / 2pi) * sum_{i<j} dot(q_i,q_j) * erf(d_ij/sqrt(2)) / d_ij
// n = 4096, n_q = 8, fp32.
// erf via Abramowitz-Stegun 7.1.26 (|err| <= 1.5e-7), branchless, with the
// 1/sqrt(2) folded into the rational-argument constant.
// j-side data read via wave-uniform global loads (scalarize to s_load, no LDS).
// Cross-block reduction: device-scope double atomicAdd + last-block-out
// (counter zeroed by a 32-byte memset node in the graph).

#define TILE   256
#define KC     32
#define CHUNKS (TILE / KC)   // 8
#define NT     16            // 4096 / TILE
#define NRECTS (NT * (NT + 1) / 2)     // 136
#define NBLOCKS (NRECTS * CHUNKS)      // 1088

#if __has_builtin(__builtin_amdgcn_exp2f)
#define EXP2F(x) __builtin_amdgcn_exp2f(x)
#else
#define EXP2F(x) __expf((x) * 0.69314718055994531f)
#endif

__device__ __forceinline__ float pair_term(float d2, float dot) {
    const float invd = __builtin_amdgcn_rsqf(d2);                 // 1/d
    const float d    = d2 * invd;                                 // d
    // erf(d/sqrt2) = 1 - poly(t)*exp(-d2/2), t = 1/(1 + (0.3275911/sqrt2) d)
    const float t = __builtin_amdgcn_rcpf(__builtin_fmaf(0.23164387f, d, 1.0f));
    const float e = EXP2F(d2 * -0.72134752044448170f);            // exp(-d2/2)
    const float p = t * (0.254829592f + t * (-0.284496736f +
                    t * (1.421413741f + t * (-1.453152027f + t * 1.061405429f))));
    const float erfv = __builtin_fmaf(-p, e, 1.0f);
    return dot * erfv * invd;
}

template <bool DIAG>
__device__ __forceinline__ float rect_loop(
    const float* __restrict__ qj, const float* __restrict__ rj,
    const float4 qa, const float4 qb,
    float rx, float ry, float rz, int j0, int i)
{
    float acc = 0.0f;
#pragma unroll 4
    for (int jj = 0; jj < KC; ++jj) {
        // wave-uniform addresses -> scalar loads
        const float dx = rj[jj * 3 + 0] - rx;
        const float dy = rj[jj * 3 + 1] - ry;
        const float dz = rj[jj * 3 + 2] - rz;
        const float d2 = dx * dx + dy * dy + dz * dz;

        float dot = qa.x * qj[jj * 8 + 0] + qa.y * qj[jj * 8 + 1]
                  + qa.z * qj[jj * 8 + 2] + qa.w * qj[jj * 8 + 3]
                  + qb.x * qj[jj * 8 + 4] + qb.y * qj[jj * 8 + 5]
                  + qb.z * qj[jj * 8 + 6] + qb.w * qj[jj * 8 + 7];

        const float term = pair_term(d2, dot);
        if (DIAG) {
            acc += (j0 + jj > i) ? term : 0.0f;  // mask j<=i (incl. inf at j==i)
        } else {
            acc += term;
        }
    }
    return acc;
}

__global__ __launch_bounds__(256) void ewald_fused_kernel(
    const float* __restrict__ q,   // [n][8]
    const float* __restrict__ r,   // [n][3]
    unsigned* __restrict__ ws,     // [0]: counter, [2..3]: double accum (zeroed)
    float* __restrict__ out)
{
    __shared__ float s_part[4];

    const int tid   = threadIdx.x;
    const int rid   = blockIdx.x / CHUNKS;
    const int chunk = blockIdx.x % CHUNKS;

    // triangular decode: rid -> (col <= row)
    int row = (int)((sqrtf(8.0f * (float)rid + 1.0f) - 1.0f) * 0.5f);
    while ((row + 1) * (row + 2) / 2 <= rid) ++row;
    while (row * (row + 1) / 2 > rid) --row;
    const int col = rid - row * (row + 1) / 2;

    const int i  = col * TILE + tid;
    const int j0 = row * TILE + chunk * KC;

    // per-lane i data
    const float4 qa = reinterpret_cast<const float4*>(q)[(size_t)i * 2];
    const float4 qb = reinterpret_cast<const float4*>(q)[(size_t)i * 2 + 1];
    const float rx = r[(size_t)i * 3 + 0];
    const float ry = r[(size_t)i * 3 + 1];
    const float rz = r[(size_t)i * 3 + 2];

    const float* __restrict__ qj = q + (size_t)j0 * 8;
    const float* __restrict__ rj = r + (size_t)j0 * 3;

    float acc = (col != row)
        ? rect_loop<false>(qj, rj, qa, qb, rx, ry, rz, j0, i)
        : rect_loop<true >(qj, rj, qa, qb, rx, ry, rz, j0, i);

    // block reduction
    for (int off = 32; off > 0; off >>= 1)
        acc += __shfl_down(acc, off, 64);
    if ((tid & 63) == 0) s_part[tid >> 6] = acc;
    __syncthreads();

    if (tid == 0) {
        const float part = s_part[0] + s_part[1] + s_part[2] + s_part[3];
        double* accum = reinterpret_cast<double*>(ws + 2);
        atomicAdd(accum, (double)part);         // device-scope HW fp64 atomic
        __threadfence();
        const unsigned old = atomicAdd(ws, 1u); // arrival counter
        if (old == NBLOCKS - 1) {
            __threadfence();
            const double tot = atomicAdd(accum, 0.0);  // atomic read of final sum
            // half-sum doubled, then * NORM/(2pi)/2  =>  * NORM/(2pi)
            out[0] = (float)(tot * (90.0474 / 6.283185307179586));
        }
    }
}

extern "C" void kernel_launch(void* const* d_in, const int* in_sizes, int n_in,
                              void* d_out, int out_size, void* d_ws, size_t ws_size,
                              hipStream_t stream) {
    const float* q = (const float*)d_in[0];   // [n, 8]
    const float* r = (const float*)d_in[1];   // [n, 3]
    float* out = (float*)d_out;

    // zero counter + double accumulator (32 B covers both, keeps alignment)
    hipMemsetAsync(d_ws, 0, 32, stream);

    ewald_fused_kernel<<<NBLOCKS, 256, 0, stream>>>(q, r, (unsigned*)d_ws, out);
}

// Round 6
// 69.611 us; speedup vs baseline: 1.2639x; 1.2639x over previous
//
#include <hip/hip_runtime.h>
#include <math.h>

// Ewald real-space pair sum, symmetric half-enumeration:
//   out = (NORM / 2pi) * sum_{i<j} dot(q_i,q_j) * erf(d_ij/sqrt(2)) / d_ij
// n = 4096, n_q = 8, fp32.
// erf via Abramowitz-Stegun 7.1.26 (|err| <= 1.5e-7), branchless, with the
// 1/sqrt(2) folded into the rational-argument constant.
// j-side data read via wave-uniform global loads (scalarize to s_load, no LDS).
// Cross-block reduction via partials array + tiny finalize kernel (atomic-free:
// 1088 single-cacheline-distinct stores beat serialized device-scope atomics,
// measured round 3 vs round 4: 69.1 vs 88.0 us).

#define TILE   256
#define KC     32
#define CHUNKS (TILE / KC)   // 8

#if __has_builtin(__builtin_amdgcn_exp2f)
#define EXP2F(x) __builtin_amdgcn_exp2f(x)
#else
#define EXP2F(x) __expf((x) * 0.69314718055994531f)
#endif

__device__ __forceinline__ float pair_term(float d2, float dot) {
    const float invd = __builtin_amdgcn_rsqf(d2);                 // 1/d
    const float d    = d2 * invd;                                 // d
    // erf(d/sqrt2) = 1 - poly(t)*exp(-d2/2), t = 1/(1 + (0.3275911/sqrt2) d)
    const float t = __builtin_amdgcn_rcpf(__builtin_fmaf(0.23164387f, d, 1.0f));
    const float e = EXP2F(d2 * -0.72134752044448170f);            // exp(-d2/2)
    const float p = t * (0.254829592f + t * (-0.284496736f +
                    t * (1.421413741f + t * (-1.453152027f + t * 1.061405429f))));
    const float erfv = __builtin_fmaf(-p, e, 1.0f);
    return dot * erfv * invd;
}

template <bool DIAG>
__device__ __forceinline__ float rect_loop(
    const float* __restrict__ qj, const float* __restrict__ rj,
    const float4 qa, const float4 qb,
    float rx, float ry, float rz, int j0, int i)
{
    float acc = 0.0f;
#pragma unroll 4
    for (int jj = 0; jj < KC; ++jj) {
        // wave-uniform addresses -> scalar loads
        const float dx = rj[jj * 3 + 0] - rx;
        const float dy = rj[jj * 3 + 1] - ry;
        const float dz = rj[jj * 3 + 2] - rz;
        const float d2 = dx * dx + dy * dy + dz * dz;

        float dot = qa.x * qj[jj * 8 + 0] + qa.y * qj[jj * 8 + 1]
                  + qa.z * qj[jj * 8 + 2] + qa.w * qj[jj * 8 + 3]
                  + qb.x * qj[jj * 8 + 4] + qb.y * qj[jj * 8 + 5]
                  + qb.z * qj[jj * 8 + 6] + qb.w * qj[jj * 8 + 7];

        const float term = pair_term(d2, dot);
        if (DIAG) {
            acc += (j0 + jj > i) ? term : 0.0f;  // mask j<=i (incl. inf at j==i)
        } else {
            acc += term;
        }
    }
    return acc;
}

__global__ __launch_bounds__(256) void ewald_pairs_kernel(
    const float* __restrict__ q,   // [n][8]
    const float* __restrict__ r,   // [n][3]
    float* __restrict__ partials)  // [gridDim.x]
{
    __shared__ float s_part[4];

    const int tid   = threadIdx.x;
    const int rid   = blockIdx.x / CHUNKS;
    const int chunk = blockIdx.x % CHUNKS;

    // triangular decode: rid -> (col <= row)
    int row = (int)((sqrtf(8.0f * (float)rid + 1.0f) - 1.0f) * 0.5f);
    while ((row + 1) * (row + 2) / 2 <= rid) ++row;
    while (row * (row + 1) / 2 > rid) --row;
    const int col = rid - row * (row + 1) / 2;

    const int i  = col * TILE + tid;
    const int j0 = row * TILE + chunk * KC;

    // per-lane i data
    const float4 qa = reinterpret_cast<const float4*>(q)[(size_t)i * 2];
    const float4 qb = reinterpret_cast<const float4*>(q)[(size_t)i * 2 + 1];
    const float rx = r[(size_t)i * 3 + 0];
    const float ry = r[(size_t)i * 3 + 1];
    const float rz = r[(size_t)i * 3 + 2];

    const float* __restrict__ qj = q + (size_t)j0 * 8;
    const float* __restrict__ rj = r + (size_t)j0 * 3;

    float acc = (col != row)
        ? rect_loop<false>(qj, rj, qa, qb, rx, ry, rz, j0, i)
        : rect_loop<true >(qj, rj, qa, qb, rx, ry, rz, j0, i);

    // block reduction -> one partial per block
    for (int off = 32; off > 0; off >>= 1)
        acc += __shfl_down(acc, off, 64);
    if ((tid & 63) == 0) s_part[tid >> 6] = acc;
    __syncthreads();
    if (tid == 0)
        partials[blockIdx.x] = s_part[0] + s_part[1] + s_part[2] + s_part[3];
}

__global__ __launch_bounds__(256) void finalize_kernel(
    const float* __restrict__ partials, float* __restrict__ out, int nb)
{
    __shared__ double sp[4];
    const int tid = threadIdx.x;
    double s = 0.0;
    for (int idx = tid; idx < nb; idx += 256) s += (double)partials[idx];
    for (int off = 32; off > 0; off >>= 1)
        s += __shfl_down(s, off, 64);
    if ((tid & 63) == 0) sp[tid >> 6] = s;
    __syncthreads();
    if (tid == 0) {
        const double tot = sp[0] + sp[1] + sp[2] + sp[3];
        // half-sum doubled, then * NORM/(2pi)/2  =>  * NORM/(2pi)
        out[0] = (float)(tot * (90.0474 / 6.283185307179586));
    }
}

extern "C" void kernel_launch(void* const* d_in, const int* in_sizes, int n_in,
                              void* d_out, int out_size, void* d_ws, size_t ws_size,
                              hipStream_t stream) {
    const float* q = (const float*)d_in[0];   // [n, 8]
    const float* r = (const float*)d_in[1];   // [n, 3]
    float* out      = (float*)d_out;
    float* partials = (float*)d_ws;

    const int n  = in_sizes[1] / 3;           // 4096
    const int nt = n / TILE;                  // 16
    const int nrects  = nt * (nt + 1) / 2;    // 136
    const int nblocks = nrects * CHUNKS;      // 1088

    ewald_pairs_kernel<<<nblocks, 256, 0, stream>>>(q, r, partials);
    finalize_kernel<<<1, 256, 0, stream>>>(partials, out, nblocks);
}